// Round 1
// baseline (1208.342 us; speedup 1.0000x reference)
//
#include <hip/hip_runtime.h>
#include <hip/hip_bf16.h>

#define BN_EPS 1e-5f

// ---------------------------------------------------------------- CSR build
__global__ void count_kernel(const int* __restrict__ dst, int* __restrict__ deg,
                             int E, int N) {
    int i = blockIdx.x * blockDim.x + threadIdx.x;
    if (i >= E) return;
    int d = dst[i];
    d = min(max(d, 0), N - 1);
    atomicAdd(&deg[d], 1);
}

__global__ __launch_bounds__(1024) void scan_kernel(const int* __restrict__ deg,
                                                    int* __restrict__ off,
                                                    int* __restrict__ cur, int N) {
    __shared__ int sm[1024];
    int t = threadIdx.x;
    int chunk = (N + 1023) / 1024;
    int lo = t * chunk, hi = min(N, lo + chunk);
    int s = 0;
    for (int i = lo; i < hi; ++i) s += deg[i];
    sm[t] = s;
    __syncthreads();
    if (t == 0) {
        int run = 0;
        for (int i = 0; i < 1024; ++i) { int v = sm[i]; sm[i] = run; run += v; }
    }
    __syncthreads();
    int run = sm[t];
    for (int i = lo; i < hi; ++i) {
        off[i] = run; cur[i] = run; run += deg[i];
    }
    if (t == 1023) off[N] = run;
}

__global__ void fill_kernel(const int* __restrict__ dst, int* __restrict__ cur,
                            int* __restrict__ elist, int E, int N) {
    int i = blockIdx.x * blockDim.x + threadIdx.x;
    if (i >= E) return;
    int d = dst[i];
    d = min(max(d, 0), N - 1);
    int p = atomicAdd(&cur[d], 1);
    elist[p] = i;
}

// ------------------------------------------------- fused message + aggregate
// t[n] = x[n] + sum_{e: dst(e)=n} relu(x[src(e)] + edge_attr[e] @ we + be)
// One wave per node. we (16 x D) held in registers: lane covers cols
// [lane*C, lane*C+C), C = D/64.
template <int D>
__global__ __launch_bounds__(256) void msg_agg_kernel(
    const float* __restrict__ x, const float* __restrict__ ea,
    const int* __restrict__ src, const int* __restrict__ off,
    const int* __restrict__ elist, const float* __restrict__ we,
    const float* __restrict__ be, float* __restrict__ t, int N) {
    constexpr int C = D / 64;
    const int lane = threadIdx.x & 63;
    const int wid = blockIdx.x * 4 + (threadIdx.x >> 6);
    if (wid >= N) return;

    float wreg[16][C];
#pragma unroll
    for (int k = 0; k < 16; ++k) {
#pragma unroll
        for (int c = 0; c < C; ++c)
            wreg[k][c] = we[k * D + lane * C + c];
    }
    float breg[C];
#pragma unroll
    for (int c = 0; c < C; ++c) breg[c] = be[lane * C + c];

    float acc[C];
#pragma unroll
    for (int c = 0; c < C; ++c) acc[c] = 0.f;

    const int i0 = off[wid], i1 = off[wid + 1];
    for (int i = i0; i < i1; ++i) {
        int e = elist[i];
        int s = src[e];
        s = min(max(s, 0), N - 1);
        float ear[16];
#pragma unroll
        for (int q = 0; q < 4; ++q)
            *(float4*)&ear[q * 4] = *(const float4*)&ea[(size_t)e * 16 + q * 4];
        float m[C];
#pragma unroll
        for (int c = 0; c < C; ++c) m[c] = breg[c];
#pragma unroll
        for (int k = 0; k < 16; ++k) {
#pragma unroll
            for (int c = 0; c < C; ++c)
                m[c] = fmaf(ear[k], wreg[k][c], m[c]);
        }
        const float* xs = &x[(size_t)s * D + lane * C];
        float xv[C];
        if constexpr (C == 4) {
            float4 v = *(const float4*)xs;
            xv[0] = v.x; xv[1] = v.y; xv[2] = v.z; xv[3] = v.w;
        } else if constexpr (C == 2) {
            float2 v = *(const float2*)xs;
            xv[0] = v.x; xv[1] = v.y;
        } else {
            xv[0] = xs[0];
        }
#pragma unroll
        for (int c = 0; c < C; ++c)
            acc[c] += fmaxf(m[c] + xv[c], 0.f);
    }

#pragma unroll
    for (int c = 0; c < C; ++c)
        t[(size_t)wid * D + lane * C + c] =
            x[(size_t)wid * D + lane * C + c] + acc[c];
}

// ------------------------------------------------------------- fp32 GEMM
// C[m, n] = epilogue( sum_k A[m,k] * W[k,n] + bias[n] )
// mode 1: relu            mode 2: bn(relu(z)) with bn params
// tile 64x64, block 256 threads, 4x4 micro-tile, BK=16
__global__ __launch_bounds__(256) void gemm_kernel(
    const float* __restrict__ A, const float* __restrict__ W,
    const float* __restrict__ bias, const float* __restrict__ bng,
    const float* __restrict__ bnb, const float* __restrict__ bnm,
    const float* __restrict__ bnv, float* __restrict__ C, int M, int N, int K,
    int mode) {
    __shared__ float As[16][68];  // [k][m], 16B-aligned rows
    __shared__ float Ws[16][68];  // [k][n]
    const int tid = threadIdx.x;
    const int tx = tid & 15, ty = tid >> 4;
    const int bm0 = blockIdx.x * 64;
    const int bn0 = blockIdx.y * 64;

    float acc[4][4];
#pragma unroll
    for (int i = 0; i < 4; ++i)
#pragma unroll
        for (int j = 0; j < 4; ++j) acc[i][j] = 0.f;

    for (int k0 = 0; k0 < K; k0 += 16) {
        {
            int r = tid >> 2;          // 0..63
            int kk = (tid & 3) * 4;    // 0,4,8,12
            int row = bm0 + r;
            float4 a;
            if (row < M)
                a = *(const float4*)&A[(size_t)row * K + k0 + kk];
            else
                a = make_float4(0.f, 0.f, 0.f, 0.f);
            As[kk + 0][r] = a.x;
            As[kk + 1][r] = a.y;
            As[kk + 2][r] = a.z;
            As[kk + 3][r] = a.w;
        }
        {
            int kk = tid >> 4;          // 0..15
            int nn = (tid & 15) * 4;    // 0..60
            float4 w = *(const float4*)&W[(size_t)(k0 + kk) * N + bn0 + nn];
            *(float4*)&Ws[kk][nn] = w;
        }
        __syncthreads();
#pragma unroll
        for (int k = 0; k < 16; ++k) {
            float4 av = *(const float4*)&As[k][ty * 4];
            float4 wv = *(const float4*)&Ws[k][tx * 4];
            float a[4] = {av.x, av.y, av.z, av.w};
            float w[4] = {wv.x, wv.y, wv.z, wv.w};
#pragma unroll
            for (int i = 0; i < 4; ++i)
#pragma unroll
                for (int j = 0; j < 4; ++j)
                    acc[i][j] = fmaf(a[i], w[j], acc[i][j]);
        }
        __syncthreads();
    }

#pragma unroll
    for (int i = 0; i < 4; ++i) {
        int row = bm0 + ty * 4 + i;
        if (row >= M) continue;
#pragma unroll
        for (int j = 0; j < 4; ++j) {
            int col = bn0 + tx * 4 + j;
            float z = acc[i][j] + bias[col];
            if (mode >= 1) z = fmaxf(z, 0.f);
            if (mode == 2)
                z = (z - bnm[col]) * rsqrtf(bnv[col] + BN_EPS) * bng[col] + bnb[col];
            C[(size_t)row * N + col] = z;
        }
    }
}

// ----------------------------------------------------------------- pooling
__global__ __launch_bounds__(256) void pool_kernel(const float* __restrict__ h,
                                                   const int* __restrict__ batch,
                                                   float* __restrict__ pooled,
                                                   int N) {
    const int lane = threadIdx.x & 63;
    const int wid = blockIdx.x * 4 + (threadIdx.x >> 6);
    if (wid >= N) return;
    int g = batch[wid];
    g = min(max(g, 0), 127);
    atomicAdd(&pooled[g * 64 + lane], h[(size_t)wid * 64 + lane]);
}

// -------------------------------------------------------------------- head
__global__ __launch_bounds__(128) void head_kernel(
    const float* __restrict__ pooled, const float* __restrict__ w1,
    const float* __restrict__ b1, const float* __restrict__ w2,
    const float* __restrict__ b2, float* __restrict__ out) {
    const int g = threadIdx.x;  // 128 graphs
    float p[64];
#pragma unroll
    for (int i = 0; i < 64; ++i) p[i] = pooled[g * 64 + i];
    float o = b2[0];
#pragma unroll
    for (int j = 0; j < 16; ++j) {
        float hsum = b1[j];
#pragma unroll
        for (int i = 0; i < 64; ++i) hsum = fmaf(p[i], w1[i * 16 + j], hsum);
        o = fmaf(fmaxf(hsum, 0.f), w2[j], o);
    }
    out[g] = o;
}

// ------------------------------------------------------------------ launch
extern "C" void kernel_launch(void* const* d_in, const int* in_sizes, int n_in,
                              void* d_out, int out_size, void* d_ws,
                              size_t ws_size, hipStream_t stream) {
    const float* x        = (const float*)d_in[0];
    const float* ea       = (const float*)d_in[1];
    const int*   ei       = (const int*)d_in[2];
    const int*   batch    = (const int*)d_in[3];
    const float* we1 = (const float*)d_in[4];
    const float* be1 = (const float*)d_in[5];
    const float* w1a = (const float*)d_in[6];
    const float* b1a = (const float*)d_in[7];
    const float* w1b = (const float*)d_in[8];
    const float* b1b = (const float*)d_in[9];
    const float* bn1g = (const float*)d_in[10];
    const float* bn1b = (const float*)d_in[11];
    const float* bn1m = (const float*)d_in[12];
    const float* bn1v = (const float*)d_in[13];
    const float* we2 = (const float*)d_in[14];
    const float* be2 = (const float*)d_in[15];
    const float* w2a = (const float*)d_in[16];
    const float* b2a = (const float*)d_in[17];
    const float* w2b = (const float*)d_in[18];
    const float* b2b = (const float*)d_in[19];
    const float* bn2g = (const float*)d_in[20];
    const float* bn2b = (const float*)d_in[21];
    const float* bn2m = (const float*)d_in[22];
    const float* bn2v = (const float*)d_in[23];
    const float* we3 = (const float*)d_in[24];
    const float* be3 = (const float*)d_in[25];
    const float* w3a = (const float*)d_in[26];
    const float* b3a = (const float*)d_in[27];
    const float* w3b = (const float*)d_in[28];
    const float* b3b = (const float*)d_in[29];
    const float* bn3g = (const float*)d_in[30];
    const float* bn3b = (const float*)d_in[31];
    const float* bn3m = (const float*)d_in[32];
    const float* bn3v = (const float*)d_in[33];
    const float* fc1w = (const float*)d_in[34];
    const float* fc1b = (const float*)d_in[35];
    const float* fc2w = (const float*)d_in[36];
    const float* fc2b = (const float*)d_in[37];

    const int N = in_sizes[0] / 64;
    const int E = in_sizes[1] / 16;
    const int* src = ei;
    const int* dst = ei + E;

    // workspace carve-up
    char* w = (char*)d_ws;
    auto alloc = [&](size_t bytes) -> void* {
        void* p = (void*)w;
        w += (bytes + 255) & ~(size_t)255;
        return p;
    };
    int* deg    = (int*)alloc((size_t)N * 4);
    int* off    = (int*)alloc((size_t)(N + 1) * 4);
    int* cur    = (int*)alloc((size_t)N * 4);
    int* elist  = (int*)alloc((size_t)E * 4);
    float* tb   = (float*)alloc((size_t)N * 256 * 4);
    float* ub   = (float*)alloc((size_t)N * 256 * 4);
    float* hb   = (float*)alloc((size_t)N * 256 * 4);
    float* pooled = (float*)alloc(128 * 64 * 4);

    hipMemsetAsync(deg, 0, (size_t)N * 4, stream);
    hipMemsetAsync(pooled, 0, 128 * 64 * 4, stream);

    int eb = (E + 255) / 256;
    count_kernel<<<eb, 256, 0, stream>>>(dst, deg, E, N);
    scan_kernel<<<1, 1024, 0, stream>>>(deg, off, cur, N);
    fill_kernel<<<eb, 256, 0, stream>>>(dst, cur, elist, E, N);

    const int nwb = (N + 3) / 4;          // waves-per-node blocks
    const int mt = (N + 63) / 64;         // gemm M tiles

    // ---- layer 1 (d 64 -> 256)
    msg_agg_kernel<64><<<nwb, 256, 0, stream>>>(x, ea, src, off, elist, we1, be1, tb, N);
    gemm_kernel<<<dim3(mt, 4), 256, 0, stream>>>(tb, w1a, b1a, nullptr, nullptr, nullptr,
                                                 nullptr, ub, N, 256, 64, 1);
    gemm_kernel<<<dim3(mt, 4), 256, 0, stream>>>(ub, w1b, b1b, bn1g, bn1b, bn1m, bn1v,
                                                 hb, N, 256, 256, 2);
    // ---- layer 2 (256 -> 128)
    msg_agg_kernel<256><<<nwb, 256, 0, stream>>>(hb, ea, src, off, elist, we2, be2, tb, N);
    gemm_kernel<<<dim3(mt, 2), 256, 0, stream>>>(tb, w2a, b2a, nullptr, nullptr, nullptr,
                                                 nullptr, ub, N, 128, 256, 1);
    gemm_kernel<<<dim3(mt, 2), 256, 0, stream>>>(ub, w2b, b2b, bn2g, bn2b, bn2m, bn2v,
                                                 hb, N, 128, 128, 2);
    // ---- layer 3 (128 -> 64)
    msg_agg_kernel<128><<<nwb, 256, 0, stream>>>(hb, ea, src, off, elist, we3, be3, tb, N);
    gemm_kernel<<<dim3(mt, 1), 256, 0, stream>>>(tb, w3a, b3a, nullptr, nullptr, nullptr,
                                                 nullptr, ub, N, 64, 128, 1);
    gemm_kernel<<<dim3(mt, 1), 256, 0, stream>>>(ub, w3b, b3b, bn3g, bn3b, bn3m, bn3v,
                                                 hb, N, 64, 64, 2);

    // ---- pool + head
    pool_kernel<<<nwb, 256, 0, stream>>>(hb, batch, pooled, N);
    head_kernel<<<1, 128, 0, stream>>>(pooled, fc1w, fc1b, fc2w, fc2b, (float*)d_out);
}